// Round 16
// baseline (395.363 us; speedup 1.0000x reference)
//
#include <hip/hip_runtime.h>

// B=4, C=512, L=2048, H=8, D=64. f32 inputs, f32 output.
// transpA: one launch: x->xT[b][l][c], w_qkv->wT[f][c], w_out->woT[f][c] (bf16)
// qkvgemm: bf16 MFMA direct-global frags -> QT[l][d]*0.125*log2e, KT[l][d], V[d][l]
// attn: transposed dataflow S^T=K.Q^T, O^T=V.P^T; 16-row waves (4096 waves);
//       single-pass exp2 softmax; packed b64 P writes; direct store to aoT[b][l][hd]
// outgemm: bf16 MFMA direct-global frags, bias, f32 store

#define LDIM 2048
#define CDIM 512
#define BATCH 4

typedef __attribute__((ext_vector_type(8))) short s16x8;
typedef __attribute__((ext_vector_type(4))) float f32x4;
typedef __attribute__((ext_vector_type(4))) unsigned short u16x4;
typedef unsigned int u32;
typedef unsigned short u16;

__device__ __forceinline__ u16 f2b(float f) {
    unsigned u = __float_as_uint(f);
    u += 0x7fffu + ((u >> 16) & 1u);   // RNE
    return (u16)(u >> 16);
}
// pack two floats -> two bf16 (round-half-up) in one u32: [hi16(b+0x8000) | hi16(a+0x8000)>>16]
__device__ __forceinline__ u32 pk2(float a, float b) {
    u32 ua = __float_as_uint(a) + 0x8000u;
    u32 ub = __float_as_uint(b) + 0x8000u;
    return __builtin_amdgcn_perm(ub, ua, 0x07060302u);  // {ub.hi16, ua.hi16}
}

// ---------------- unified transpose + f32->bf16 convert (one launch) ----------------
__global__ __launch_bounds__(256)
void transpA_k(const float* __restrict__ x, const float* __restrict__ wq,
               const float* __restrict__ wo, u16* __restrict__ xT,
               u16* __restrict__ wT, u16* __restrict__ woT)
{
    const int r0 = blockIdx.x * 64;   // c-dim tile (input rows), 0..511
    const int y  = blockIdx.y;
    const float* in; u16* out; int inLD, c0;
    if (y < 128) {              // x: per batch [512][2048]
        const int b = y >> 5, ct = y & 31;
        in = x + (size_t)b * CDIM * LDIM; inLD = LDIM; c0 = ct * 64;
        out = xT + (size_t)b * LDIM * CDIM;
    } else if (y < 152) {       // w_qkv [512][1536]
        in = wq; inLD = 1536; c0 = (y - 128) * 64; out = wT;
    } else {                    // w_out [512][512]
        in = wo; inLD = 512;  c0 = (y - 152) * 64; out = woT;
    }

    __shared__ __align__(16) u16 t[64][80];
    const int tt = threadIdx.x;
    const int lr = tt >> 4, lc = (tt & 15) * 4;
    #pragma unroll
    for (int i = 0; i < 4; ++i) {
        f32x4 v = *(const f32x4*)(in + (size_t)(r0 + lr + i * 16) * inLD + c0 + lc);
        #pragma unroll
        for (int j = 0; j < 4; ++j) t[lc + j][lr + i * 16] = f2b(v[j]);
    }
    __syncthreads();
    const int orow = tt >> 2, ocg = (tt & 3) * 16;
    s16x8 v0 = *(const s16x8*)&t[orow][ocg];
    s16x8 v1 = *(const s16x8*)&t[orow][ocg + 8];
    u16* dst = out + (size_t)(c0 + orow) * CDIM + r0 + ocg;
    *(s16x8*)dst = v0;
    *(s16x8*)(dst + 8) = v1;
}

// ---------------- QKV GEMM (unchanged) ----------------
__global__ __launch_bounds__(256)
void qkvgemm_bf16(const u16* __restrict__ xT, const u16* __restrict__ wT,
                  u16* __restrict__ QT, u16* __restrict__ KT, u16* __restrict__ V)
{
    const int f0 = blockIdx.x * 64;
    const int l0 = blockIdx.y * 128;
    const int b  = blockIdx.z;
    const u16* xTb = xT + (size_t)b * LDIM * CDIM;
    const int t = threadIdx.x, w = t >> 6, lane = t & 63;
    const int mn = lane & 15, q = lane >> 4;
    const bool vpart = (f0 >= 1024);

    const u16 *Abase, *Bbase;
    int mbase, nbase;
    if (!vpart) {
        mbase = f0 + (w >> 1) * 32; nbase = l0 + (w & 1) * 64;
        Abase = wT + (size_t)mbase * CDIM; Bbase = xTb + (size_t)nbase * CDIM;
    } else {
        mbase = l0 + w * 32; nbase = f0;
        Abase = xTb + (size_t)mbase * CDIM; Bbase = wT + (size_t)nbase * CDIM;
    }

    f32x4 acc[2][4] = {};
    #pragma unroll 2
    for (int c0 = 0; c0 < CDIM; c0 += 32) {
        s16x8 a[2], bf[4];
        #pragma unroll
        for (int mi = 0; mi < 2; ++mi)
            a[mi] = *(const s16x8*)(Abase + (size_t)(mi * 16 + mn) * CDIM + c0 + q * 8);
        #pragma unroll
        for (int ni = 0; ni < 4; ++ni)
            bf[ni] = *(const s16x8*)(Bbase + (size_t)(ni * 16 + mn) * CDIM + c0 + q * 8);
        #pragma unroll
        for (int mi = 0; mi < 2; ++mi)
            #pragma unroll
            for (int ni = 0; ni < 4; ++ni)
                acc[mi][ni] = __builtin_amdgcn_mfma_f32_16x16x32_bf16(a[mi], bf[ni], acc[mi][ni], 0, 0, 0);
    }

    if (!vpart) {
        const int part = f0 >> 9;
        const float sc2 = (part == 0) ? 0.18033688f : 1.0f;  // 0.125*log2(e)
        u16* Tout = (part == 0) ? QT : KT;
        #pragma unroll
        for (int mi = 0; mi < 2; ++mi) {
            const int fg0 = mbase + mi * 16;
            const int h = (fg0 >> 6) & 7;
            const int d0 = (fg0 & 63) + q * 4;
            u16* T = Tout + (size_t)(b * 8 + h) * LDIM * 64;
            #pragma unroll
            for (int ni = 0; ni < 4; ++ni) {
                const int lg = nbase + ni * 16 + mn;
                u16x4 pk;
                #pragma unroll
                for (int r = 0; r < 4; ++r) pk[r] = f2b(acc[mi][ni][r] * sc2);
                *(u16x4*)(T + (size_t)lg * 64 + d0) = pk;
            }
        }
    } else {
        #pragma unroll
        for (int ni = 0; ni < 4; ++ni) {
            const int fg = nbase + ni * 16 + mn;
            const int h = (fg >> 6) & 7;
            const int d = fg & 63;
            u16* Vb = V + (size_t)((b * 8 + h) * 64 + d) * LDIM;
            #pragma unroll
            for (int mi = 0; mi < 2; ++mi) {
                const int lg0 = mbase + mi * 16 + q * 4;
                u16x4 pk;
                #pragma unroll
                for (int r = 0; r < 4; ++r) pk[r] = f2b(acc[mi][ni][r]);
                *(u16x4*)(Vb + lg0) = pk;
            }
        }
    }
}

// ---------------- Flash attention: transposed dataflow, 16-row waves ----------------
// grid (x=bh 32, y=128), 64 threads. block_id % 8 == h: XCD head pinning.
// S^T = K.Q^T -> lane(mn,q) holds (i=mn, j=jt*16+q*4+r): 4 consecutive j per lane.
// O^T = V.P^T -> lane(mn,q) holds (i=mn, d=dt*16+q*4+r): direct aoT store.
__global__ __launch_bounds__(64)
void attn_k(const u16* __restrict__ QT, const u16* __restrict__ KT,
            const u16* __restrict__ V, u16* __restrict__ aoT)
{
    const int bh = blockIdx.x;
    const int b = bh >> 3, h = bh & 7;
    const u16* Qh = QT + (size_t)bh * LDIM * 64;
    const u16* Kh = KT + (size_t)bh * LDIM * 64;
    const u16* Vh = V  + (size_t)bh * 64 * LDIM;

    __shared__ __align__(16) u16 ldsP[2][16][72];   // [buf][i][j] (wave-private)

    const int lane = threadIdx.x;
    const int mn = lane & 15, q = lane >> 4;
    const int iw = blockIdx.y * 16;

    // Q B-frags: B[k=d][n=i], lane(mn,q) -> QT[iw+mn][kd*32+q*8..]
    s16x8 aq[2];
    #pragma unroll
    for (int kd = 0; kd < 2; ++kd)
        aq[kd] = *(const s16x8*)(Qh + (size_t)(iw + mn) * 64 + kd * 32 + q * 8);

    f32x4 o_acc[4] = {};
    float lp = 0.f;

    for (int j0 = 0; j0 < LDIM; j0 += 64) {
        const int buf = (j0 >> 6) & 1;

        // S^T: A = K-frag [m=j][k=d]
        f32x4 s[4] = {};
        #pragma unroll
        for (int kd = 0; kd < 2; ++kd)
            #pragma unroll
            for (int jt = 0; jt < 4; ++jt) {
                s16x8 bk = *(const s16x8*)(Kh + (size_t)(j0 + jt * 16 + mn) * 64 + kd * 32 + q * 8);
                s[jt] = __builtin_amdgcn_mfma_f32_16x16x32_bf16(bk, aq[kd], s[jt], 0, 0, 0);
            }

        // p = exp2(s) (scale folded into Q); pack 4 -> b64 LDS write; scalar lp
        #pragma unroll
        for (int jt = 0; jt < 4; ++jt) {
            float p0 = exp2f(s[jt][0]);
            float p1 = exp2f(s[jt][1]);
            float p2 = exp2f(s[jt][2]);
            float p3 = exp2f(s[jt][3]);
            u32 w0 = pk2(p0, p1);
            u32 w1 = pk2(p2, p3);
            uint2 wv = { w0, w1 };
            *(uint2*)&ldsP[buf][mn][jt * 16 + q * 4] = wv;
            lp += (p0 + p1) + (p2 + p3);
        }

        // O^T += V.P^T : A = V-frag [m=d][k=j], B = P^T [k=j][n=i] from LDS
        #pragma unroll
        for (int kj = 0; kj < 2; ++kj) {
            s16x8 ap = *(const s16x8*)&ldsP[buf][mn][kj * 32 + q * 8];
            #pragma unroll
            for (int dt = 0; dt < 4; ++dt) {
                s16x8 bv = *(const s16x8*)(Vh + (size_t)(dt * 16 + mn) * LDIM + j0 + kj * 32 + q * 8);
                o_acc[dt] = __builtin_amdgcn_mfma_f32_16x16x32_bf16(bv, ap, o_acc[dt], 0, 0, 0);
            }
        }
    }

    // lp: reduce over the 4 q-groups (lanes with same mn): xor 16, 32
    lp += __shfl_xor(lp, 16);
    lp += __shfl_xor(lp, 32);
    const float rinv = 1.0f / lp;

    // store: lane(mn,q) holds O[i=iw+mn][d=dt*16+q*4+r]
    u16* dst = aoT + ((size_t)b * LDIM + iw + mn) * 512 + h * 64 + q * 4;
    #pragma unroll
    for (int dt = 0; dt < 4; ++dt) {
        u16x4 pk;
        #pragma unroll
        for (int r = 0; r < 4; ++r)
            pk[r] = f2b(o_acc[dt][r] * rinv);
        *(u16x4*)(dst + dt * 16) = pk;
    }
}

// ---------------- Output GEMM: direct-global frags, bias, f32 store ----------------
__global__ __launch_bounds__(256)
void outgemm_d(const u16* __restrict__ aoT, const u16* __restrict__ woT,
               const float* __restrict__ bias, float* __restrict__ Y)
{
    const int f0 = blockIdx.x * 64;
    const int l0 = blockIdx.y * 128;
    const int b  = blockIdx.z;
    const int t = threadIdx.x, w = t >> 6, lane = t & 63;
    const int mn = lane & 15, q = lane >> 4;
    const int mbase = f0 + (w >> 1) * 32;
    const int nbase = l0 + (w & 1) * 64;
    const u16* Abase = woT + (size_t)mbase * CDIM;
    const u16* Bbase = aoT + ((size_t)b * LDIM + nbase) * CDIM;
    float* Yb = Y + (size_t)b * CDIM * LDIM;

    f32x4 acc[2][4] = {};
    #pragma unroll 2
    for (int c0 = 0; c0 < CDIM; c0 += 32) {
        s16x8 a[2], bf[4];
        #pragma unroll
        for (int mi = 0; mi < 2; ++mi)
            a[mi] = *(const s16x8*)(Abase + (size_t)(mi * 16 + mn) * CDIM + c0 + q * 8);
        #pragma unroll
        for (int ni = 0; ni < 4; ++ni)
            bf[ni] = *(const s16x8*)(Bbase + (size_t)(ni * 16 + mn) * CDIM + c0 + q * 8);
        #pragma unroll
        for (int mi = 0; mi < 2; ++mi)
            #pragma unroll
            for (int ni = 0; ni < 4; ++ni)
                acc[mi][ni] = __builtin_amdgcn_mfma_f32_16x16x32_bf16(a[mi], bf[ni], acc[mi][ni], 0, 0, 0);
    }
    #pragma unroll
    for (int mi = 0; mi < 2; ++mi)
        #pragma unroll
        for (int r = 0; r < 4; ++r) {
            const int f = mbase + mi * 16 + q * 4 + r;
            const float bs = bias[f];
            #pragma unroll
            for (int ni = 0; ni < 4; ++ni)
                Yb[(size_t)f * LDIM + nbase + ni * 16 + mn] = acc[mi][ni][r] + bs;
        }
}

extern "C" void kernel_launch(void* const* d_in, const int* in_sizes, int n_in,
                              void* d_out, int out_size, void* d_ws, size_t ws_size,
                              hipStream_t stream) {
    const float *x = nullptr, *w_qkv = nullptr, *w_out = nullptr, *b_out = nullptr;
    for (int i = 0; i < n_in; ++i) {
        switch (in_sizes[i]) {
            case 4 * 512 * 2048: x     = (const float*)d_in[i]; break;
            case 512 * 1536:     w_qkv = (const float*)d_in[i]; break;
            case 512 * 512:      w_out = (const float*)d_in[i]; break;
            case 512:            b_out = (const float*)d_in[i]; break;
        }
    }
    float* out = (float*)d_out;                 // [4][512][2048] f32

    // --- workspace layout, no aliasing (44.1 MB; 67 MB proven safe r3) ---
    const size_t SLAB = (size_t)BATCH * LDIM * 512;      // 4194304 elems
    u16* woT = (u16*)d_ws;                               // [512][512]
    u16* xT  = woT + (size_t)512 * 512;                  // [4][2048][512]
    u16* wT  = xT + SLAB;                                // [1536][512]
    u16* QT  = wT + (size_t)1536 * 512;                  // [32][2048][64]
    u16* KT  = QT + SLAB;                                // [32][2048][64]
    u16* V   = KT + SLAB;                                // [32][64][2048]
    u16* aoT = V + SLAB;                                 // [4][2048][512]

    transpA_k<<<dim3(8, 160), 256, 0, stream>>>(x, w_qkv, w_out, xT, wT, woT);
    qkvgemm_bf16<<<dim3(24, 16, BATCH), 256, 0, stream>>>(xT, wT, QT, KT, V);
    attn_k<<<dim3(BATCH * 8, LDIM / 16), 64, 0, stream>>>(QT, KT, V, aoT);
    outgemm_d<<<dim3(8, 16, BATCH), 256, 0, stream>>>(aoT, woT, b_out, out);
}

// Round 17
// 290.416 us; speedup vs baseline: 1.3614x; 1.3614x over previous
//
#include <hip/hip_runtime.h>

// B=4, C=512, L=2048, H=8, D=64. f32 inputs, f32 output.
// transpA: one launch: x->xT[b][l][c], w_qkv->wT[f][c], w_out->woT[f][c] (bf16)
// qkvgemm: bf16 MFMA direct-global frags -> QT[l][d]*0.125*log2e, KT[l][d], V[d][l]
// attn: transposed dataflow S^T=K.Q^T, O^T=V.P^T; 32 i-rows/wave (2 subtiles,
//       K/V frags shared); v_exp_f32 softmax; b64 packed P; direct aoT store
// outgemm: bf16 MFMA direct-global frags, bias, f32 store

#define LDIM 2048
#define CDIM 512
#define BATCH 4

typedef __attribute__((ext_vector_type(8))) short s16x8;
typedef __attribute__((ext_vector_type(4))) float f32x4;
typedef __attribute__((ext_vector_type(4))) unsigned short u16x4;
typedef unsigned int u32;
typedef unsigned short u16;

__device__ __forceinline__ u16 f2b(float f) {
    unsigned u = __float_as_uint(f);
    u += 0x7fffu + ((u >> 16) & 1u);   // RNE
    return (u16)(u >> 16);
}
// pack two floats -> two bf16 (round-half-up) in one u32 (p1 in high half)
__device__ __forceinline__ u32 pk2(float a, float b) {
    u32 ua = __float_as_uint(a) + 0x8000u;
    u32 ub = __float_as_uint(b) + 0x8000u;
    return __builtin_amdgcn_perm(ub, ua, 0x07060302u);  // {ub.hi16, ua.hi16}
}

// ---------------- unified transpose + f32->bf16 convert ----------------
__global__ __launch_bounds__(256)
void transpA_k(const float* __restrict__ x, const float* __restrict__ wq,
               const float* __restrict__ wo, u16* __restrict__ xT,
               u16* __restrict__ wT, u16* __restrict__ woT)
{
    const int r0 = blockIdx.x * 64;
    const int y  = blockIdx.y;
    const float* in; u16* out; int inLD, c0;
    if (y < 128) {
        const int b = y >> 5, ct = y & 31;
        in = x + (size_t)b * CDIM * LDIM; inLD = LDIM; c0 = ct * 64;
        out = xT + (size_t)b * LDIM * CDIM;
    } else if (y < 152) {
        in = wq; inLD = 1536; c0 = (y - 128) * 64; out = wT;
    } else {
        in = wo; inLD = 512;  c0 = (y - 152) * 64; out = woT;
    }

    __shared__ __align__(16) u16 t[64][80];
    const int tt = threadIdx.x;
    const int lr = tt >> 4, lc = (tt & 15) * 4;
    #pragma unroll
    for (int i = 0; i < 4; ++i) {
        f32x4 v = *(const f32x4*)(in + (size_t)(r0 + lr + i * 16) * inLD + c0 + lc);
        #pragma unroll
        for (int j = 0; j < 4; ++j) t[lc + j][lr + i * 16] = f2b(v[j]);
    }
    __syncthreads();
    const int orow = tt >> 2, ocg = (tt & 3) * 16;
    s16x8 v0 = *(const s16x8*)&t[orow][ocg];
    s16x8 v1 = *(const s16x8*)&t[orow][ocg + 8];
    u16* dst = out + (size_t)(c0 + orow) * CDIM + r0 + ocg;
    *(s16x8*)dst = v0;
    *(s16x8*)(dst + 8) = v1;
}

// ---------------- QKV GEMM (unchanged) ----------------
__global__ __launch_bounds__(256)
void qkvgemm_bf16(const u16* __restrict__ xT, const u16* __restrict__ wT,
                  u16* __restrict__ QT, u16* __restrict__ KT, u16* __restrict__ V)
{
    const int f0 = blockIdx.x * 64;
    const int l0 = blockIdx.y * 128;
    const int b  = blockIdx.z;
    const u16* xTb = xT + (size_t)b * LDIM * CDIM;
    const int t = threadIdx.x, w = t >> 6, lane = t & 63;
    const int mn = lane & 15, q = lane >> 4;
    const bool vpart = (f0 >= 1024);

    const u16 *Abase, *Bbase;
    int mbase, nbase;
    if (!vpart) {
        mbase = f0 + (w >> 1) * 32; nbase = l0 + (w & 1) * 64;
        Abase = wT + (size_t)mbase * CDIM; Bbase = xTb + (size_t)nbase * CDIM;
    } else {
        mbase = l0 + w * 32; nbase = f0;
        Abase = xTb + (size_t)mbase * CDIM; Bbase = wT + (size_t)nbase * CDIM;
    }

    f32x4 acc[2][4] = {};
    #pragma unroll 2
    for (int c0 = 0; c0 < CDIM; c0 += 32) {
        s16x8 a[2], bf[4];
        #pragma unroll
        for (int mi = 0; mi < 2; ++mi)
            a[mi] = *(const s16x8*)(Abase + (size_t)(mi * 16 + mn) * CDIM + c0 + q * 8);
        #pragma unroll
        for (int ni = 0; ni < 4; ++ni)
            bf[ni] = *(const s16x8*)(Bbase + (size_t)(ni * 16 + mn) * CDIM + c0 + q * 8);
        #pragma unroll
        for (int mi = 0; mi < 2; ++mi)
            #pragma unroll
            for (int ni = 0; ni < 4; ++ni)
                acc[mi][ni] = __builtin_amdgcn_mfma_f32_16x16x32_bf16(a[mi], bf[ni], acc[mi][ni], 0, 0, 0);
    }

    if (!vpart) {
        const int part = f0 >> 9;
        const float sc2 = (part == 0) ? 0.18033688f : 1.0f;  // 0.125*log2(e)
        u16* Tout = (part == 0) ? QT : KT;
        #pragma unroll
        for (int mi = 0; mi < 2; ++mi) {
            const int fg0 = mbase + mi * 16;
            const int h = (fg0 >> 6) & 7;
            const int d0 = (fg0 & 63) + q * 4;
            u16* T = Tout + (size_t)(b * 8 + h) * LDIM * 64;
            #pragma unroll
            for (int ni = 0; ni < 4; ++ni) {
                const int lg = nbase + ni * 16 + mn;
                u16x4 pk;
                #pragma unroll
                for (int r = 0; r < 4; ++r) pk[r] = f2b(acc[mi][ni][r] * sc2);
                *(u16x4*)(T + (size_t)lg * 64 + d0) = pk;
            }
        }
    } else {
        #pragma unroll
        for (int ni = 0; ni < 4; ++ni) {
            const int fg = nbase + ni * 16 + mn;
            const int h = (fg >> 6) & 7;
            const int d = fg & 63;
            u16* Vb = V + (size_t)((b * 8 + h) * 64 + d) * LDIM;
            #pragma unroll
            for (int mi = 0; mi < 2; ++mi) {
                const int lg0 = mbase + mi * 16 + q * 4;
                u16x4 pk;
                #pragma unroll
                for (int r = 0; r < 4; ++r) pk[r] = f2b(acc[mi][ni][r]);
                *(u16x4*)(Vb + lg0) = pk;
            }
        }
    }
}

// ---------------- Flash attention: transposed dataflow, 32 i-rows/wave ----------------
// grid (x=bh 32, y=64), 64 threads (1 wave). block_id % 8 == h: XCD head pinning.
// S^T = K.Q^T -> lane(mn,q): i=mn, j=jt*16+q*4+r (4 consecutive j).
// O^T = V.P^T -> lane(mn,q): i=mn, d=dt*16+q*4+r -> direct aoT store.
__global__ __launch_bounds__(64)
void attn_k(const u16* __restrict__ QT, const u16* __restrict__ KT,
            const u16* __restrict__ V, u16* __restrict__ aoT)
{
    const int bh = blockIdx.x;
    const int b = bh >> 3, h = bh & 7;
    const u16* Qh = QT + (size_t)bh * LDIM * 64;
    const u16* Kh = KT + (size_t)bh * LDIM * 64;
    const u16* Vh = V  + (size_t)bh * 64 * LDIM;

    __shared__ __align__(16) u16 ldsP[2][2][16][72];   // [buf][ibt][i][j]

    const int lane = threadIdx.x;
    const int mn = lane & 15, q = lane >> 4;
    const int iw = blockIdx.y * 32;

    // Q B-frags per ibt: B[k=d][n=i]
    s16x8 aq[2][2];
    #pragma unroll
    for (int ibt = 0; ibt < 2; ++ibt)
        #pragma unroll
        for (int kd = 0; kd < 2; ++kd)
            aq[ibt][kd] = *(const s16x8*)(Qh + (size_t)(iw + ibt * 16 + mn) * 64 + kd * 32 + q * 8);

    f32x4 o_acc[2][4] = {};
    float lp[2] = {0.f, 0.f};

    #pragma unroll 2
    for (int j0 = 0; j0 < LDIM; j0 += 64) {
        const int buf = (j0 >> 6) & 1;

        // K A-frags (shared across ibt): A[m=j][k=d]
        s16x8 bk[2][4];
        #pragma unroll
        for (int kd = 0; kd < 2; ++kd)
            #pragma unroll
            for (int jt = 0; jt < 4; ++jt)
                bk[kd][jt] = *(const s16x8*)(Kh + (size_t)(j0 + jt * 16 + mn) * 64 + kd * 32 + q * 8);

        f32x4 s[2][4] = {};
        #pragma unroll
        for (int kd = 0; kd < 2; ++kd)
            #pragma unroll
            for (int jt = 0; jt < 4; ++jt) {
                s[0][jt] = __builtin_amdgcn_mfma_f32_16x16x32_bf16(bk[kd][jt], aq[0][kd], s[0][jt], 0, 0, 0);
                s[1][jt] = __builtin_amdgcn_mfma_f32_16x16x32_bf16(bk[kd][jt], aq[1][kd], s[1][jt], 0, 0, 0);
            }

        // p = 2^s (scale folded into Q); raw v_exp_f32; b64 packed writes; scalar lp
        #pragma unroll
        for (int ibt = 0; ibt < 2; ++ibt)
            #pragma unroll
            for (int jt = 0; jt < 4; ++jt) {
                float p0 = __builtin_amdgcn_exp2f(s[ibt][jt][0]);
                float p1 = __builtin_amdgcn_exp2f(s[ibt][jt][1]);
                float p2 = __builtin_amdgcn_exp2f(s[ibt][jt][2]);
                float p3 = __builtin_amdgcn_exp2f(s[ibt][jt][3]);
                uint2 wv = { pk2(p0, p1), pk2(p2, p3) };
                *(uint2*)&ldsP[buf][ibt][mn][jt * 16 + q * 4] = wv;
                lp[ibt] += (p0 + p1) + (p2 + p3);
            }

        // O^T += V.P^T : A = V-frag (shared), B = P^T from LDS per ibt
        #pragma unroll
        for (int kj = 0; kj < 2; ++kj) {
            s16x8 ap0 = *(const s16x8*)&ldsP[buf][0][mn][kj * 32 + q * 8];
            s16x8 ap1 = *(const s16x8*)&ldsP[buf][1][mn][kj * 32 + q * 8];
            #pragma unroll
            for (int dt = 0; dt < 4; ++dt) {
                s16x8 bv = *(const s16x8*)(Vh + (size_t)(dt * 16 + mn) * LDIM + j0 + kj * 32 + q * 8);
                o_acc[0][dt] = __builtin_amdgcn_mfma_f32_16x16x32_bf16(bv, ap0, o_acc[0][dt], 0, 0, 0);
                o_acc[1][dt] = __builtin_amdgcn_mfma_f32_16x16x32_bf16(bv, ap1, o_acc[1][dt], 0, 0, 0);
            }
        }
    }

    // lp: reduce over the 4 q-groups (same mn): xor 16, 32
    #pragma unroll
    for (int ibt = 0; ibt < 2; ++ibt) {
        lp[ibt] += __shfl_xor(lp[ibt], 16);
        lp[ibt] += __shfl_xor(lp[ibt], 32);
    }

    // store: lane(mn,q) holds O[i=iw+ibt*16+mn][d=dt*16+q*4+r]
    #pragma unroll
    for (int ibt = 0; ibt < 2; ++ibt) {
        const float rinv = 1.0f / lp[ibt];
        u16* dst = aoT + ((size_t)b * LDIM + iw + ibt * 16 + mn) * 512 + h * 64 + q * 4;
        #pragma unroll
        for (int dt = 0; dt < 4; ++dt) {
            u16x4 pk;
            #pragma unroll
            for (int r = 0; r < 4; ++r)
                pk[r] = f2b(o_acc[ibt][dt][r] * rinv);
            *(u16x4*)(dst + dt * 16) = pk;
        }
    }
}

// ---------------- Output GEMM (unchanged) ----------------
__global__ __launch_bounds__(256)
void outgemm_d(const u16* __restrict__ aoT, const u16* __restrict__ woT,
               const float* __restrict__ bias, float* __restrict__ Y)
{
    const int f0 = blockIdx.x * 64;
    const int l0 = blockIdx.y * 128;
    const int b  = blockIdx.z;
    const int t = threadIdx.x, w = t >> 6, lane = t & 63;
    const int mn = lane & 15, q = lane >> 4;
    const int mbase = f0 + (w >> 1) * 32;
    const int nbase = l0 + (w & 1) * 64;
    const u16* Abase = woT + (size_t)mbase * CDIM;
    const u16* Bbase = aoT + ((size_t)b * LDIM + nbase) * CDIM;
    float* Yb = Y + (size_t)b * CDIM * LDIM;

    f32x4 acc[2][4] = {};
    #pragma unroll 2
    for (int c0 = 0; c0 < CDIM; c0 += 32) {
        s16x8 a[2], bf[4];
        #pragma unroll
        for (int mi = 0; mi < 2; ++mi)
            a[mi] = *(const s16x8*)(Abase + (size_t)(mi * 16 + mn) * CDIM + c0 + q * 8);
        #pragma unroll
        for (int ni = 0; ni < 4; ++ni)
            bf[ni] = *(const s16x8*)(Bbase + (size_t)(ni * 16 + mn) * CDIM + c0 + q * 8);
        #pragma unroll
        for (int mi = 0; mi < 2; ++mi)
            #pragma unroll
            for (int ni = 0; ni < 4; ++ni)
                acc[mi][ni] = __builtin_amdgcn_mfma_f32_16x16x32_bf16(a[mi], bf[ni], acc[mi][ni], 0, 0, 0);
    }
    #pragma unroll
    for (int mi = 0; mi < 2; ++mi)
        #pragma unroll
        for (int r = 0; r < 4; ++r) {
            const int f = mbase + mi * 16 + q * 4 + r;
            const float bs = bias[f];
            #pragma unroll
            for (int ni = 0; ni < 4; ++ni)
                Yb[(size_t)f * LDIM + nbase + ni * 16 + mn] = acc[mi][ni][r] + bs;
        }
}

extern "C" void kernel_launch(void* const* d_in, const int* in_sizes, int n_in,
                              void* d_out, int out_size, void* d_ws, size_t ws_size,
                              hipStream_t stream) {
    const float *x = nullptr, *w_qkv = nullptr, *w_out = nullptr, *b_out = nullptr;
    for (int i = 0; i < n_in; ++i) {
        switch (in_sizes[i]) {
            case 4 * 512 * 2048: x     = (const float*)d_in[i]; break;
            case 512 * 1536:     w_qkv = (const float*)d_in[i]; break;
            case 512 * 512:      w_out = (const float*)d_in[i]; break;
            case 512:            b_out = (const float*)d_in[i]; break;
        }
    }
    float* out = (float*)d_out;                 // [4][512][2048] f32

    const size_t SLAB = (size_t)BATCH * LDIM * 512;      // 4194304 elems
    u16* woT = (u16*)d_ws;                               // [512][512]
    u16* xT  = woT + (size_t)512 * 512;                  // [4][2048][512]
    u16* wT  = xT + SLAB;                                // [1536][512]
    u16* QT  = wT + (size_t)1536 * 512;                  // [32][2048][64]
    u16* KT  = QT + SLAB;                                // [32][2048][64]
    u16* V   = KT + SLAB;                                // [32][64][2048]
    u16* aoT = V + SLAB;                                 // [4][2048][512]

    transpA_k<<<dim3(8, 160), 256, 0, stream>>>(x, w_qkv, w_out, xT, wT, woT);
    qkvgemm_bf16<<<dim3(24, 16, BATCH), 256, 0, stream>>>(xT, wT, QT, KT, V);
    attn_k<<<dim3(BATCH * 8, LDIM / 32), 64, 0, stream>>>(QT, KT, V, aoT);
    outgemm_d<<<dim3(8, 16, BATCH), 256, 0, stream>>>(aoT, woT, b_out, out);
}

// Round 18
// 290.395 us; speedup vs baseline: 1.3615x; 1.0001x over previous
//
#include <hip/hip_runtime.h>

// B=4, C=512, L=2048, H=8, D=64. f32 inputs, f32 output.
// transpA: one launch: x->xT[b][l][c], w_qkv->wT[f][c], w_out->woT[f][c] (bf16)
// qkvgemm: bf16 MFMA direct-global frags -> QT[l][d]*0.125*log2e, KT[l][d], V[d][l]
// attn: transposed dataflow S^T=K.Q^T, O^T=V.P^T; 32 i-rows/wave; v_exp_f32;
//       *** register-prefetch pipeline: K/V frags for iter n+1 issued before iter n's
//       compute (hides ~2000cyc of exposed L2 latency measured in r17) ***
// outgemm: bf16 MFMA direct-global frags, bias, f32 store

#define LDIM 2048
#define CDIM 512
#define BATCH 4

typedef __attribute__((ext_vector_type(8))) short s16x8;
typedef __attribute__((ext_vector_type(4))) float f32x4;
typedef __attribute__((ext_vector_type(4))) unsigned short u16x4;
typedef unsigned int u32;
typedef unsigned short u16;

__device__ __forceinline__ u16 f2b(float f) {
    unsigned u = __float_as_uint(f);
    u += 0x7fffu + ((u >> 16) & 1u);   // RNE
    return (u16)(u >> 16);
}
// pack two floats -> two bf16 (round-half-up) in one u32 (b in high half)
__device__ __forceinline__ u32 pk2(float a, float b) {
    u32 ua = __float_as_uint(a) + 0x8000u;
    u32 ub = __float_as_uint(b) + 0x8000u;
    return __builtin_amdgcn_perm(ub, ua, 0x07060302u);  // {ub.hi16, ua.hi16}
}

// ---------------- unified transpose + f32->bf16 convert ----------------
__global__ __launch_bounds__(256)
void transpA_k(const float* __restrict__ x, const float* __restrict__ wq,
               const float* __restrict__ wo, u16* __restrict__ xT,
               u16* __restrict__ wT, u16* __restrict__ woT)
{
    const int r0 = blockIdx.x * 64;
    const int y  = blockIdx.y;
    const float* in; u16* out; int inLD, c0;
    if (y < 128) {
        const int b = y >> 5, ct = y & 31;
        in = x + (size_t)b * CDIM * LDIM; inLD = LDIM; c0 = ct * 64;
        out = xT + (size_t)b * LDIM * CDIM;
    } else if (y < 152) {
        in = wq; inLD = 1536; c0 = (y - 128) * 64; out = wT;
    } else {
        in = wo; inLD = 512;  c0 = (y - 152) * 64; out = woT;
    }

    __shared__ __align__(16) u16 t[64][80];
    const int tt = threadIdx.x;
    const int lr = tt >> 4, lc = (tt & 15) * 4;
    #pragma unroll
    for (int i = 0; i < 4; ++i) {
        f32x4 v = *(const f32x4*)(in + (size_t)(r0 + lr + i * 16) * inLD + c0 + lc);
        #pragma unroll
        for (int j = 0; j < 4; ++j) t[lc + j][lr + i * 16] = f2b(v[j]);
    }
    __syncthreads();
    const int orow = tt >> 2, ocg = (tt & 3) * 16;
    s16x8 v0 = *(const s16x8*)&t[orow][ocg];
    s16x8 v1 = *(const s16x8*)&t[orow][ocg + 8];
    u16* dst = out + (size_t)(c0 + orow) * CDIM + r0 + ocg;
    *(s16x8*)dst = v0;
    *(s16x8*)(dst + 8) = v1;
}

// ---------------- QKV GEMM (unchanged) ----------------
__global__ __launch_bounds__(256)
void qkvgemm_bf16(const u16* __restrict__ xT, const u16* __restrict__ wT,
                  u16* __restrict__ QT, u16* __restrict__ KT, u16* __restrict__ V)
{
    const int f0 = blockIdx.x * 64;
    const int l0 = blockIdx.y * 128;
    const int b  = blockIdx.z;
    const u16* xTb = xT + (size_t)b * LDIM * CDIM;
    const int t = threadIdx.x, w = t >> 6, lane = t & 63;
    const int mn = lane & 15, q = lane >> 4;
    const bool vpart = (f0 >= 1024);

    const u16 *Abase, *Bbase;
    int mbase, nbase;
    if (!vpart) {
        mbase = f0 + (w >> 1) * 32; nbase = l0 + (w & 1) * 64;
        Abase = wT + (size_t)mbase * CDIM; Bbase = xTb + (size_t)nbase * CDIM;
    } else {
        mbase = l0 + w * 32; nbase = f0;
        Abase = xTb + (size_t)mbase * CDIM; Bbase = wT + (size_t)nbase * CDIM;
    }

    f32x4 acc[2][4] = {};
    #pragma unroll 2
    for (int c0 = 0; c0 < CDIM; c0 += 32) {
        s16x8 a[2], bf[4];
        #pragma unroll
        for (int mi = 0; mi < 2; ++mi)
            a[mi] = *(const s16x8*)(Abase + (size_t)(mi * 16 + mn) * CDIM + c0 + q * 8);
        #pragma unroll
        for (int ni = 0; ni < 4; ++ni)
            bf[ni] = *(const s16x8*)(Bbase + (size_t)(ni * 16 + mn) * CDIM + c0 + q * 8);
        #pragma unroll
        for (int mi = 0; mi < 2; ++mi)
            #pragma unroll
            for (int ni = 0; ni < 4; ++ni)
                acc[mi][ni] = __builtin_amdgcn_mfma_f32_16x16x32_bf16(a[mi], bf[ni], acc[mi][ni], 0, 0, 0);
    }

    if (!vpart) {
        const int part = f0 >> 9;
        const float sc2 = (part == 0) ? 0.18033688f : 1.0f;  // 0.125*log2(e)
        u16* Tout = (part == 0) ? QT : KT;
        #pragma unroll
        for (int mi = 0; mi < 2; ++mi) {
            const int fg0 = mbase + mi * 16;
            const int h = (fg0 >> 6) & 7;
            const int d0 = (fg0 & 63) + q * 4;
            u16* T = Tout + (size_t)(b * 8 + h) * LDIM * 64;
            #pragma unroll
            for (int ni = 0; ni < 4; ++ni) {
                const int lg = nbase + ni * 16 + mn;
                u16x4 pk;
                #pragma unroll
                for (int r = 0; r < 4; ++r) pk[r] = f2b(acc[mi][ni][r] * sc2);
                *(u16x4*)(T + (size_t)lg * 64 + d0) = pk;
            }
        }
    } else {
        #pragma unroll
        for (int ni = 0; ni < 4; ++ni) {
            const int fg = nbase + ni * 16 + mn;
            const int h = (fg >> 6) & 7;
            const int d = fg & 63;
            u16* Vb = V + (size_t)((b * 8 + h) * 64 + d) * LDIM;
            #pragma unroll
            for (int mi = 0; mi < 2; ++mi) {
                const int lg0 = mbase + mi * 16 + q * 4;
                u16x4 pk;
                #pragma unroll
                for (int r = 0; r < 4; ++r) pk[r] = f2b(acc[mi][ni][r]);
                *(u16x4*)(Vb + lg0) = pk;
            }
        }
    }
}

// ---------------- Flash attention: prefetch-pipelined, 32 i-rows/wave ----------------
// grid (x=bh 32, y=64), 64 threads (1 wave). block_id % 8 == h: XCD head pinning.
__global__ __launch_bounds__(64)
void attn_k(const u16* __restrict__ QT, const u16* __restrict__ KT,
            const u16* __restrict__ V, u16* __restrict__ aoT)
{
    const int bh = blockIdx.x;
    const int b = bh >> 3, h = bh & 7;
    const u16* Qh = QT + (size_t)bh * LDIM * 64;
    const u16* Kh = KT + (size_t)bh * LDIM * 64;
    const u16* Vh = V  + (size_t)bh * 64 * LDIM;

    __shared__ __align__(16) u16 ldsP[2][2][16][72];   // [buf][ibt][i][j]

    const int lane = threadIdx.x;
    const int mn = lane & 15, q = lane >> 4;
    const int iw = blockIdx.y * 32;

    s16x8 aq[2][2];
    #pragma unroll
    for (int ibt = 0; ibt < 2; ++ibt)
        #pragma unroll
        for (int kd = 0; kd < 2; ++kd)
            aq[ibt][kd] = *(const s16x8*)(Qh + (size_t)(iw + ibt * 16 + mn) * 64 + kd * 32 + q * 8);

    f32x4 o_acc[2][4] = {};
    float lp[2] = {0.f, 0.f};

    // preload iteration-0 K/V fragments
    s16x8 kc[2][4], vc[2][4];
    #pragma unroll
    for (int kd = 0; kd < 2; ++kd)
        #pragma unroll
        for (int jt = 0; jt < 4; ++jt)
            kc[kd][jt] = *(const s16x8*)(Kh + (size_t)(jt * 16 + mn) * 64 + kd * 32 + q * 8);
    #pragma unroll
    for (int kj = 0; kj < 2; ++kj)
        #pragma unroll
        for (int dt = 0; dt < 4; ++dt)
            vc[kj][dt] = *(const s16x8*)(Vh + (size_t)(dt * 16 + mn) * LDIM + kj * 32 + q * 8);

    #pragma unroll 2
    for (int j0 = 0; j0 < LDIM; j0 += 64) {
        const int buf = (j0 >> 6) & 1;
        const int jn = (j0 + 64) & (LDIM - 1);   // last iter wraps to 0 (harmless, L2-hot)

        // issue next tile's loads FIRST (one full iteration of latency hiding)
        s16x8 kn[2][4], vn[2][4];
        #pragma unroll
        for (int kd = 0; kd < 2; ++kd)
            #pragma unroll
            for (int jt = 0; jt < 4; ++jt)
                kn[kd][jt] = *(const s16x8*)(Kh + (size_t)(jn + jt * 16 + mn) * 64 + kd * 32 + q * 8);
        #pragma unroll
        for (int kj = 0; kj < 2; ++kj)
            #pragma unroll
            for (int dt = 0; dt < 4; ++dt)
                vn[kj][dt] = *(const s16x8*)(Vh + (size_t)(dt * 16 + mn) * LDIM + jn + kj * 32 + q * 8);

        // S^T = K.Q^T on current K
        f32x4 s[2][4] = {};
        #pragma unroll
        for (int kd = 0; kd < 2; ++kd)
            #pragma unroll
            for (int jt = 0; jt < 4; ++jt) {
                s[0][jt] = __builtin_amdgcn_mfma_f32_16x16x32_bf16(kc[kd][jt], aq[0][kd], s[0][jt], 0, 0, 0);
                s[1][jt] = __builtin_amdgcn_mfma_f32_16x16x32_bf16(kc[kd][jt], aq[1][kd], s[1][jt], 0, 0, 0);
            }

        // p = 2^s; packed b64 LDS writes; scalar lp
        #pragma unroll
        for (int ibt = 0; ibt < 2; ++ibt)
            #pragma unroll
            for (int jt = 0; jt < 4; ++jt) {
                float p0 = __builtin_amdgcn_exp2f(s[ibt][jt][0]);
                float p1 = __builtin_amdgcn_exp2f(s[ibt][jt][1]);
                float p2 = __builtin_amdgcn_exp2f(s[ibt][jt][2]);
                float p3 = __builtin_amdgcn_exp2f(s[ibt][jt][3]);
                uint2 wv = { pk2(p0, p1), pk2(p2, p3) };
                *(uint2*)&ldsP[buf][ibt][mn][jt * 16 + q * 4] = wv;
                lp[ibt] += (p0 + p1) + (p2 + p3);
            }

        // O^T += V.P^T on current V
        #pragma unroll
        for (int kj = 0; kj < 2; ++kj) {
            s16x8 ap0 = *(const s16x8*)&ldsP[buf][0][mn][kj * 32 + q * 8];
            s16x8 ap1 = *(const s16x8*)&ldsP[buf][1][mn][kj * 32 + q * 8];
            #pragma unroll
            for (int dt = 0; dt < 4; ++dt) {
                o_acc[0][dt] = __builtin_amdgcn_mfma_f32_16x16x32_bf16(vc[kj][dt], ap0, o_acc[0][dt], 0, 0, 0);
                o_acc[1][dt] = __builtin_amdgcn_mfma_f32_16x16x32_bf16(vc[kj][dt], ap1, o_acc[1][dt], 0, 0, 0);
            }
        }

        // rotate prefetched registers
        #pragma unroll
        for (int kd = 0; kd < 2; ++kd)
            #pragma unroll
            for (int jt = 0; jt < 4; ++jt)
                kc[kd][jt] = kn[kd][jt];
        #pragma unroll
        for (int kj = 0; kj < 2; ++kj)
            #pragma unroll
            for (int dt = 0; dt < 4; ++dt)
                vc[kj][dt] = vn[kj][dt];
    }

    #pragma unroll
    for (int ibt = 0; ibt < 2; ++ibt) {
        lp[ibt] += __shfl_xor(lp[ibt], 16);
        lp[ibt] += __shfl_xor(lp[ibt], 32);
    }

    #pragma unroll
    for (int ibt = 0; ibt < 2; ++ibt) {
        const float rinv = 1.0f / lp[ibt];
        u16* dst = aoT + ((size_t)b * LDIM + iw + ibt * 16 + mn) * 512 + h * 64 + q * 4;
        #pragma unroll
        for (int dt = 0; dt < 4; ++dt) {
            u16x4 pk;
            #pragma unroll
            for (int r = 0; r < 4; ++r)
                pk[r] = f2b(o_acc[ibt][dt][r] * rinv);
            *(u16x4*)(dst + dt * 16) = pk;
        }
    }
}

// ---------------- Output GEMM (unchanged) ----------------
__global__ __launch_bounds__(256)
void outgemm_d(const u16* __restrict__ aoT, const u16* __restrict__ woT,
               const float* __restrict__ bias, float* __restrict__ Y)
{
    const int f0 = blockIdx.x * 64;
    const int l0 = blockIdx.y * 128;
    const int b  = blockIdx.z;
    const int t = threadIdx.x, w = t >> 6, lane = t & 63;
    const int mn = lane & 15, q = lane >> 4;
    const int mbase = f0 + (w >> 1) * 32;
    const int nbase = l0 + (w & 1) * 64;
    const u16* Abase = woT + (size_t)mbase * CDIM;
    const u16* Bbase = aoT + ((size_t)b * LDIM + nbase) * CDIM;
    float* Yb = Y + (size_t)b * CDIM * LDIM;

    f32x4 acc[2][4] = {};
    #pragma unroll 2
    for (int c0 = 0; c0 < CDIM; c0 += 32) {
        s16x8 a[2], bf[4];
        #pragma unroll
        for (int mi = 0; mi < 2; ++mi)
            a[mi] = *(const s16x8*)(Abase + (size_t)(mi * 16 + mn) * CDIM + c0 + q * 8);
        #pragma unroll
        for (int ni = 0; ni < 4; ++ni)
            bf[ni] = *(const s16x8*)(Bbase + (size_t)(ni * 16 + mn) * CDIM + c0 + q * 8);
        #pragma unroll
        for (int mi = 0; mi < 2; ++mi)
            #pragma unroll
            for (int ni = 0; ni < 4; ++ni)
                acc[mi][ni] = __builtin_amdgcn_mfma_f32_16x16x32_bf16(a[mi], bf[ni], acc[mi][ni], 0, 0, 0);
    }
    #pragma unroll
    for (int mi = 0; mi < 2; ++mi)
        #pragma unroll
        for (int r = 0; r < 4; ++r) {
            const int f = mbase + mi * 16 + q * 4 + r;
            const float bs = bias[f];
            #pragma unroll
            for (int ni = 0; ni < 4; ++ni)
                Yb[(size_t)f * LDIM + nbase + ni * 16 + mn] = acc[mi][ni][r] + bs;
        }
}

extern "C" void kernel_launch(void* const* d_in, const int* in_sizes, int n_in,
                              void* d_out, int out_size, void* d_ws, size_t ws_size,
                              hipStream_t stream) {
    const float *x = nullptr, *w_qkv = nullptr, *w_out = nullptr, *b_out = nullptr;
    for (int i = 0; i < n_in; ++i) {
        switch (in_sizes[i]) {
            case 4 * 512 * 2048: x     = (const float*)d_in[i]; break;
            case 512 * 1536:     w_qkv = (const float*)d_in[i]; break;
            case 512 * 512:      w_out = (const float*)d_in[i]; break;
            case 512:            b_out = (const float*)d_in[i]; break;
        }
    }
    float* out = (float*)d_out;                 // [4][512][2048] f32

    const size_t SLAB = (size_t)BATCH * LDIM * 512;      // 4194304 elems
    u16* woT = (u16*)d_ws;                               // [512][512]
    u16* xT  = woT + (size_t)512 * 512;                  // [4][2048][512]
    u16* wT  = xT + SLAB;                                // [1536][512]
    u16* QT  = wT + (size_t)1536 * 512;                  // [32][2048][64]
    u16* KT  = QT + SLAB;                                // [32][2048][64]
    u16* V   = KT + SLAB;                                // [32][64][2048]
    u16* aoT = V + SLAB;                                 // [4][2048][512]

    transpA_k<<<dim3(8, 160), 256, 0, stream>>>(x, w_qkv, w_out, xT, wT, woT);
    qkvgemm_bf16<<<dim3(24, 16, BATCH), 256, 0, stream>>>(xT, wT, QT, KT, V);
    attn_k<<<dim3(BATCH * 8, LDIM / 32), 64, 0, stream>>>(QT, KT, V, aoT);
    outgemm_d<<<dim3(8, 16, BATCH), 256, 0, stream>>>(aoT, woT, b_out, out);
}